// Round 1
// baseline (215.749 us; speedup 1.0000x reference)
//
#include <hip/hip_runtime.h>

#define SS 1024
#define GG 10
#define FF 5
#define BB 8
#define CC 3

// ---------------------------------------------------------------------------
// Kernel 1: smooth the (B,1,G,G) offset grids with an 11x11 gaussian
// (edge-padded), scale by max_offset, clip, store field [B][2][G][G] in ws.
// ---------------------------------------------------------------------------
__global__ __launch_bounds__(256) void rds_smooth_kernel(
    const float* __restrict__ ox, const float* __restrict__ oy,
    const float* __restrict__ w, const void* __restrict__ max_move_p,
    float* __restrict__ gs)
{
    int idx = blockIdx.x * 256 + threadIdx.x;
    if (idx >= BB * 2 * GG * GG) return;
    int j  = idx % GG;
    int i  = (idx / GG) % GG;
    int ch = (idx / (GG * GG)) % 2;
    int b  = idx / (2 * GG * GG);

    const float* o = (ch == 0 ? ox : oy) + b * GG * GG;

    // max_move: python scalar; hedge int32 vs float32 storage
    int mi = *(const int*)max_move_p;
    float mv = (mi >= -100000 && mi <= 100000) ? (float)mi : __int_as_float(mi);
    float max_offset = 2.0f * mv / (float)SS;

    float acc = 0.0f;
    for (int u = 0; u < 2 * FF + 1; ++u) {
        int yy = min(max(i + u - FF, 0), GG - 1);
        for (int v = 0; v < 2 * FF + 1; ++v) {
            int xx = min(max(j + v - FF, 0), GG - 1);
            acc += o[yy * GG + xx] * w[u * (2 * FF + 1) + v];
        }
    }
    acc *= max_offset;
    acc = fminf(fmaxf(acc, -max_offset), max_offset);
    gs[idx] = acc;
}

// ---------------------------------------------------------------------------
// Kernel 2: upsample field 10x10 -> 1024x1024 (separable bilinear), add base
// grid, clip to [-1,1], then bilinear grid-sample x (zero-pad masks) for all
// 3 channels. One thread per output pixel; block = 256 consecutive columns.
// ---------------------------------------------------------------------------
__global__ __launch_bounds__(256) void rds_deform_kernel(
    const float* __restrict__ x, const float* __restrict__ gs,
    float* __restrict__ out)
{
    // gridDim.x = BB * SS * (SS/256); decode (b, y, xseg)
    int bx   = blockIdx.x;
    int xseg = bx & 3;                 // SS/256 = 4
    int y    = (bx >> 2) & (SS - 1);   // 1024 rows
    int b    = bx >> 12;               // / 4096
    int xc   = xseg * 256 + threadIdx.x;

    __shared__ float g0[GG * GG];
    __shared__ float g1[GG * GG];
    if (threadIdx.x < GG * GG) {
        g0[threadIdx.x] = gs[(b * 2 + 0) * GG * GG + threadIdx.x];
        g1[threadIdx.x] = gs[(b * 2 + 1) * GG * GG + threadIdx.x];
    }
    __syncthreads();

    const float GdS = (float)GG / (float)SS;

    // separable bilinear upsample coords (rows then cols, same as reference)
    float sy  = fmaxf(((float)y + 0.5f) * GdS - 0.5f, 0.0f);
    int   i0y = min((int)floorf(sy), GG - 1);
    int   i1y = min(i0y + 1, GG - 1);
    float wyu = sy - (float)i0y;

    float sx  = fmaxf(((float)xc + 0.5f) * GdS - 0.5f, 0.0f);
    int   i0x = min((int)floorf(sx), GG - 1);
    int   i1x = min(i0x + 1, GG - 1);
    float wxu = sx - (float)i0x;

    float a00 = g0[i0y * GG + i0x], a10 = g0[i1y * GG + i0x];
    float a01 = g0[i0y * GG + i1x], a11 = g0[i1y * GG + i1x];
    float gxv = (a00 * (1.0f - wyu) + a10 * wyu) * (1.0f - wxu)
              + (a01 * (1.0f - wyu) + a11 * wyu) * wxu;

    float b00 = g1[i0y * GG + i0x], b10 = g1[i1y * GG + i0x];
    float b01 = g1[i0y * GG + i1x], b11 = g1[i1y * GG + i1x];
    float gyv = (b00 * (1.0f - wyu) + b10 * wyu) * (1.0f - wxu)
              + (b01 * (1.0f - wyu) + b11 * wyu) * wxu;

    // base grid P (align_corners-style lin: i/(S-1) * 2 - 1)
    float px = (float)xc * (2.0f / (float)(SS - 1)) - 1.0f;
    float py = (float)y  * (2.0f / (float)(SS - 1)) - 1.0f;

    float gr0 = fminf(fmaxf(gxv + px, -1.0f), 1.0f);
    float gr1 = fminf(fmaxf(gyv + py, -1.0f), 1.0f);

    // grid-sample coords (align_corners=False convention in reference)
    float ix = ((gr0 + 1.0f) * (float)SS - 1.0f) * 0.5f;
    float iy = ((gr1 + 1.0f) * (float)SS - 1.0f) * 0.5f;

    int   x0 = (int)floorf(ix);
    int   x1 = x0 + 1;
    int   y0 = (int)floorf(iy);
    int   y1 = y0 + 1;
    float wx = ix - (float)x0;
    float wy = iy - (float)y0;

    float m_x0 = (x0 >= 0 && x0 < SS) ? 1.0f : 0.0f;
    float m_x1 = (x1 >= 0 && x1 < SS) ? 1.0f : 0.0f;
    float m_y0 = (y0 >= 0 && y0 < SS) ? 1.0f : 0.0f;
    float m_y1 = (y1 >= 0 && y1 < SS) ? 1.0f : 0.0f;

    float w00 = (1.0f - wy) * (1.0f - wx) * m_y0 * m_x0;
    float w01 = (1.0f - wy) * wx          * m_y0 * m_x1;
    float w10 = wy          * (1.0f - wx) * m_y1 * m_x0;
    float w11 = wy          * wx          * m_y1 * m_x1;

    int cx0 = min(max(x0, 0), SS - 1);
    int cx1 = min(max(x1, 0), SS - 1);
    int cy0 = min(max(y0, 0), SS - 1);
    int cy1 = min(max(y1, 0), SS - 1);

    const float* xb = x + (size_t)b * CC * SS * SS;
    size_t o00 = (size_t)cy0 * SS + cx0;
    size_t o01 = (size_t)cy0 * SS + cx1;
    size_t o10 = (size_t)cy1 * SS + cx0;
    size_t o11 = (size_t)cy1 * SS + cx1;

    #pragma unroll
    for (int c = 0; c < CC; ++c) {
        const float* img = xb + (size_t)c * SS * SS;
        float v = img[o00] * w00 + img[o01] * w01
                + img[o10] * w10 + img[o11] * w11;
        out[(((size_t)b * CC + c) * SS + y) * SS + xc] = v;
    }
}

extern "C" void kernel_launch(void* const* d_in, const int* in_sizes, int n_in,
                              void* d_out, int out_size, void* d_ws, size_t ws_size,
                              hipStream_t stream) {
    const float* x        = (const float*)d_in[0];
    const float* offset_x = (const float*)d_in[1];
    const float* offset_y = (const float*)d_in[2];
    const float* weight   = (const float*)d_in[3];
    const void*  max_move = d_in[4];
    float* out = (float*)d_out;
    float* gs  = (float*)d_ws;   // [B][2][G][G] smoothed, scaled, clipped field

    int n1 = BB * 2 * GG * GG;   // 1600
    rds_smooth_kernel<<<(n1 + 255) / 256, 256, 0, stream>>>(
        offset_x, offset_y, weight, max_move, gs);

    int nblocks = BB * SS * (SS / 256);  // 8 * 1024 * 4 = 32768
    rds_deform_kernel<<<nblocks, 256, 0, stream>>>(x, gs, out);
}